// Round 8
// baseline (193.801 us; speedup 1.0000x reference)
//
#include <hip/hip_runtime.h>

// PFNN: 4 branches of 3->32->32->32->1 tanh MLP, N=1M points, fp32 in/out.
// Round 15: eliminate the transcendentals. R14 model: 384 exp2/thread at
// quarter-rate (16cy) = 60% of wall; packed-FP32 confirmed full-rate and
// issue-bound (removed ops -> 1:1 wall time). So replace exp2-tanh with the
// [7/6] continued-fraction approximant, fully packed:
//   tanh(x) = x(s^3+378s^2+17325s+135135)/(28s^3+3150s^2+62370s+135135),
//   s=x^2, clamp |x|<=5 via fmed3. Max err ~1e-4 on [0,5] (verified at
//   x=0.5,1,2,3,4,4.5,5); clamp err <=9.2e-5; >1 overshoot (1.0000098)
//   truncates to 1.0 under RTZ f16. Coefficients f32-exact (<2^24); den
//   product <=3e26 (no overflow). Batched rcp kept: 1 v_rcp per 4 tanh.
//   Per tanh4: 4 exp2+1 rcp+8pk (96cy) -> 4 med3+27pk+1 rcp (~70cy).
// Weights now stored PLAIN (no SCALE, no -2 fold) - h is true tanh in f16.
//   - kept: packed f32x2 pairs (v0,v2),(v1,v3), tree dot8, uint4 W3 loads,
//     float2 bias pairs, MFMA L0 (hi/lo f16 split), HROW=80 b128 A-reads,
//     launch_bounds(256,8), per-wave LDS h tile.

#define NPTS 1048576
#define BLOCK 256
#define HROW 80          // bytes per h row in LDS (16B aligned)

// ws layout (bytes):
// 0..16383   : WfH [2][4][2][16][32] f16 (hidden weights, plain, permuted)
#define OFF_BSC  16384   // Bsc [2][4][16] float2 (hidden bias pairs, plain)
#define OFF_W0F  17408   // W0f [4][2][16][32] f16 (L0 hi/lo packed, plain)
#define OFF_B0P  25600   // B0p [4][16] float2 (L0 bias pairs, plain)
#define OFF_W3P  26112   // W3p [4][16] u32 (f16 pairs of w3, plain)

using f16   = _Float16;
using f16x8 = __attribute__((ext_vector_type(8))) _Float16;  // MFMA A/B frag
using f32x4 = __attribute__((ext_vector_type(4))) float;     // MFMA C/D frag
using f32x2 = __attribute__((ext_vector_type(2))) float;     // packed-f32 pair
using hfx2  = decltype(__builtin_amdgcn_cvt_pkrtz(0.0f, 0.0f)); // __fp16x2

__device__ __forceinline__ f32x2 pk_fma2(f32x2 a, f32x2 b, f32x2 c) {
#if __has_builtin(__builtin_elementwise_fma)
    return __builtin_elementwise_fma(a, b, c);
#else
    f32x2 d = {__builtin_fmaf(a[0], b[0], c[0]), __builtin_fmaf(a[1], b[1], c[1])};
    return d;
#endif
}

// 4 tanh via [7/6] continued fraction, packed pairs X=(v0,v2), Y=(v1,v3),
// batched reciprocal (ONE v_rcp for all 4 denominators).
__device__ __forceinline__ void tanh4_cf(float v0, float v1, float v2, float v3,
                                         float& o0, float& o1, float& o2, float& o3)
{
    float c0 = __builtin_amdgcn_fmed3f(v0, -5.0f, 5.0f);
    float c1 = __builtin_amdgcn_fmed3f(v1, -5.0f, 5.0f);
    float c2 = __builtin_amdgcn_fmed3f(v2, -5.0f, 5.0f);
    float c3 = __builtin_amdgcn_fmed3f(v3, -5.0f, 5.0f);
    f32x2 X = {c0, c2};
    f32x2 Y = {c1, c3};
    f32x2 SX = X * X;
    f32x2 SY = Y * Y;
    const f32x2 k378    = {378.0f, 378.0f};
    const f32x2 k17325  = {17325.0f, 17325.0f};
    const f32x2 k135135 = {135135.0f, 135135.0f};
    const f32x2 k28     = {28.0f, 28.0f};
    const f32x2 k3150   = {3150.0f, 3150.0f};
    const f32x2 k62370  = {62370.0f, 62370.0f};
    // num = x*(((s+378)s+17325)s+135135)
    f32x2 NX = SX + k378;
    NX = pk_fma2(NX, SX, k17325);
    NX = pk_fma2(NX, SX, k135135);
    NX = NX * X;
    f32x2 NY = SY + k378;
    NY = pk_fma2(NY, SY, k17325);
    NY = pk_fma2(NY, SY, k135135);
    NY = NY * Y;
    // den = ((28s+3150)s+62370)s+135135
    f32x2 DX = pk_fma2(k28, SX, k3150);
    DX = pk_fma2(DX, SX, k62370);
    DX = pk_fma2(DX, SX, k135135);
    f32x2 DY = pk_fma2(k28, SY, k3150);
    DY = pk_fma2(DY, SY, k62370);
    DY = pk_fma2(DY, SY, k135135);
    // batched reciprocal of 4 denominators
    f32x2 P2 = DX * DY;                         // (d0*d1, d2*d3)
    float p  = P2[0] * P2[1];
    float r  = __builtin_amdgcn_rcpf(p);
    f32x2 rr = {r, r};
    f32x2 Ps = __builtin_shufflevector(P2, P2, 1, 0);  // (d2d3, d0d1)
    f32x2 T  = rr * Ps;                          // (1/(d0d1), 1/(d2d3))
    f32x2 iDX = T * DY;                          // (1/d0, 1/d2)
    f32x2 iDY = T * DX;                          // (1/d1, 1/d3)
    f32x2 HX = NX * iDX;                         // (tanh v0, tanh v2)
    f32x2 HY = NY * iDY;                         // (tanh v1, tanh v3)
    o0 = HX[0]; o1 = HY[0]; o2 = HX[1]; o3 = HY[1];
}

// per-mt epilogue: tanh4 over (c0[r],c1[r],c0[r+1],c1[r+1]) -> 2 packed b32
__device__ __forceinline__ void epi_mt(const f32x4& c0, const f32x4& c1, int mt,
                                       unsigned char* __restrict__ H,
                                       int col, int quad)
{
    #pragma unroll
    for (int r = 0; r < 4; r += 2) {
        int p = mt * 16 + quad * 4 + r;
        float o0, o1, o2, o3;
        tanh4_cf(c0[r], c1[r], c0[r + 1], c1[r + 1], o0, o1, o2, o3);
        union { hfx2 h; unsigned int u; } cv0, cv1;
        cv0.h = __builtin_amdgcn_cvt_pkrtz(o0, o1);
        cv1.h = __builtin_amdgcn_cvt_pkrtz(o2, o3);
        *reinterpret_cast<unsigned int*>(H + p * HROW + 4 * col)       = cv0.u;
        *reinterpret_cast<unsigned int*>(H + (p + 1) * HROW + 4 * col) = cv1.u;
    }
}

// layer 0 for branch b: 3 -> 32 via MFMA on xfrag (fp32-equivalent)
__device__ __forceinline__ void layer0_block(int b, const f16x8 (&xfrag)[4],
                                             const f16* __restrict__ W0f,
                                             const float* __restrict__ B0p,
                                             unsigned char* __restrict__ H,
                                             int col, int quad)
{
    const f16* wb = W0f + (b * 2) * 512;
    f16x8 bf0 = *reinterpret_cast<const f16x8*>(wb + col * 32 + quad * 8);
    f16x8 bf1 = *reinterpret_cast<const f16x8*>(wb + 512 + col * 32 + quad * 8);
    const float2 bp = *reinterpret_cast<const float2*>(B0p + ((b * 16 + col) << 1));
    f32x4 ci0 = {bp.x, bp.x, bp.x, bp.x};   // shared C operand, all mt
    f32x4 ci1 = {bp.y, bp.y, bp.y, bp.y};

    #pragma unroll
    for (int mt = 0; mt < 4; ++mt) {
        f32x4 c0 = __builtin_amdgcn_mfma_f32_16x16x32_f16(xfrag[mt], bf0, ci0, 0, 0, 0);
        f32x4 c1 = __builtin_amdgcn_mfma_f32_16x16x32_f16(xfrag[mt], bf1, ci1, 0, 0, 0);
        epi_mt(c0, c1, mt, H, col, quad);
    }
}

// hidden layer l (0->L1, 1->L2) for branch b: 32 -> 32 via MFMA from H
__device__ __forceinline__ void hidden_block(int l, int b,
                                             const f16* __restrict__ Wf,
                                             const float* __restrict__ Bsc,
                                             unsigned char* __restrict__ H,
                                             int col, int quad)
{
    const f16* wb = Wf + ((l * 4 + b) * 2) * 512;
    f16x8 bf0 = *reinterpret_cast<const f16x8*>(wb + col * 32 + quad * 8);
    f16x8 bf1 = *reinterpret_cast<const f16x8*>(wb + 512 + col * 32 + quad * 8);
    const float2 bp = *reinterpret_cast<const float2*>(
        Bsc + (((l * 4 + b) * 16 + col) << 1));
    f32x4 ci0 = {bp.x, bp.x, bp.x, bp.x};   // shared C operand, all mt
    f32x4 ci1 = {bp.y, bp.y, bp.y, bp.y};

    #pragma unroll
    for (int mt = 0; mt < 4; ++mt) {
        const f16x8 av = *reinterpret_cast<const f16x8*>(
            H + (mt * 16 + col) * HROW + quad * 16);   // 16B aligned
        f32x4 c0 = __builtin_amdgcn_mfma_f32_16x16x32_f16(av, bf0, ci0, 0, 0, 0);
        f32x4 c1 = __builtin_amdgcn_mfma_f32_16x16x32_f16(av, bf1, ci1, 0, 0, 0);
        epi_mt(c0, c1, mt, H, col, quad);
    }
}

// 8-element f16 dot: acc += sum(u[i]*w[i]) via fdot2/fma
__device__ __forceinline__ float dot8(unsigned int ux, unsigned int uy,
                                      unsigned int uz, unsigned int uw,
                                      uint4 w, float acc)
{
#if __has_builtin(__builtin_amdgcn_fdot2)
    union { unsigned int uu; hfx2 hh; } a0, a1, a2, a3, b0, b1, b2, b3;
    a0.uu = ux; a1.uu = uy; a2.uu = uz; a3.uu = uw;
    b0.uu = w.x; b1.uu = w.y; b2.uu = w.z; b3.uu = w.w;
    acc = __builtin_amdgcn_fdot2(a0.hh, b0.hh, acc, false);
    acc = __builtin_amdgcn_fdot2(a1.hh, b1.hh, acc, false);
    acc = __builtin_amdgcn_fdot2(a2.hh, b2.hh, acc, false);
    acc = __builtin_amdgcn_fdot2(a3.hh, b3.hh, acc, false);
#else
    union { unsigned int uu; f16 h[2]; } a[4], bw[4];
    a[0].uu = ux; a[1].uu = uy; a[2].uu = uz; a[3].uu = uw;
    bw[0].uu = w.x; bw[1].uu = w.y; bw[2].uu = w.z; bw[3].uu = w.w;
    #pragma unroll
    for (int q = 0; q < 4; ++q) {
        acc = __builtin_fmaf((float)a[q].h[0], (float)bw[q].h[0], acc);
        acc = __builtin_fmaf((float)a[q].h[1], (float)bw[q].h[1], acc);
    }
#endif
    return acc;
}

__global__ void prep_kernel(const float* __restrict__ W0, const float* __restrict__ b0,
                            const float* __restrict__ W1, const float* __restrict__ b1,
                            const float* __restrict__ W2, const float* __restrict__ b2,
                            const float* __restrict__ W3,
                            unsigned char* __restrict__ ws)
{
    int i = blockIdx.x * 256 + threadIdx.x;
    if (i < 8192) {
        // WfH[l][b][t][n][k] = W_l[b][k][2n+t]  (f16, plain)
        int k = i & 31, n = (i >> 5) & 15, t = (i >> 9) & 1, b = (i >> 10) & 3, l = i >> 12;
        int f = 2 * n + t;
        const float* W = l ? W2 : W1;
        reinterpret_cast<f16*>(ws)[i] = (f16)(W[(b * 32 + k) * 32 + f]);
    } else if (i < 8448) {
        // Bsc pairs: [(l*4+b)*16+n] -> (bias_even, bias_odd)
        int j = i - 8192;
        int n = j & 15, t = (j >> 4) & 1, b = (j >> 5) & 3, l = j >> 7;
        const float* bb = l ? b2 : b1;
        reinterpret_cast<float*>(ws + OFF_BSC)[(((l * 4 + b) * 16 + n) << 1) | t]
            = bb[b * 32 + 2 * n + t];
    } else if (i < 12544) {
        // W0f[b][t][n][k]: quad q = k>>3, jj = k&7.
        //   q==0, jj<3 : Wh row jj      (pairs with xh -> xh*Wh)
        //   q==0, 3<=jj<6 : Wh row jj-3 (pairs with xl -> xl*Wh)
        //   q==1, jj<3 : Wl row jj      (pairs with xh -> xh*Wl)
        //   else 0
        int j = i - 8448;
        int k = j & 31, n = (j >> 5) & 15, t = (j >> 9) & 1, b = (j >> 10) & 3;
        int f = 2 * n + t;
        int q = k >> 3, jj = k & 7;
        int row = -1; bool lo = false;
        if (q == 0 && jj < 6)      row = (jj < 3) ? jj : jj - 3;
        else if (q == 1 && jj < 3) { row = jj; lo = true; }
        f16 outv = (f16)0.0f;
        if (row >= 0) {
            float w  = W0[(b * 3 + row) * 32 + f];
            f16   wh = (f16)w;
            outv = lo ? (f16)(w - (float)wh) : wh;
        }
        reinterpret_cast<f16*>(ws + OFF_W0F)[((b * 2 + t) * 16 + n) * 32 + k] = outv;
    } else if (i < 12672) {
        // B0p pairs: [b*16+n] -> (bias_even, bias_odd)
        int j = i - 12544;
        int n = j & 15, t = (j >> 4) & 1, b = j >> 5;
        reinterpret_cast<float*>(ws + OFF_B0P)[(((b) * 16 + n) << 1) | t]
            = b0[b * 32 + 2 * n + t];
    } else if (i < 12736) {
        int j = i - 12672;              // j = b*16 + pair
        union { hfx2 h; unsigned int u; } cv;
        cv.h = __builtin_amdgcn_cvt_pkrtz(W3[2 * j], W3[2 * j + 1]);
        reinterpret_cast<unsigned int*>(ws + OFF_W3P)[j] = cv.u;
    }
}

__global__ __launch_bounds__(BLOCK, 8) void pfnn_kernel(
    const float* __restrict__ x, const unsigned char* __restrict__ ws,
    const float* __restrict__ b3,
    float* __restrict__ out)
{
    __shared__ __align__(16) unsigned char Hl[4][64 * HROW]; // per-wave h tile

    const f16*   Wf  = reinterpret_cast<const f16*>(ws);
    const float* Bsc = reinterpret_cast<const float*>(ws + OFF_BSC);
    const f16*   W0f = reinterpret_cast<const f16*>(ws + OFF_W0F);
    const float* B0p = reinterpret_cast<const float*>(ws + OFF_B0P);
    const unsigned int* W3p = reinterpret_cast<const unsigned int*>(ws + OFF_W3P);

    const int t    = threadIdx.x;
    const int lane = t & 63;
    const int wv   = t >> 6;
    const int col  = lane & 15;
    const int quad = lane >> 4;
    unsigned char* __restrict__ H = &Hl[wv][0];

    const int n0 = blockIdx.x * BLOCK + t;
    const float x0 = x[3 * n0 + 0];
    const float x1 = x[3 * n0 + 1];
    const float x2 = x[3 * n0 + 2];

    // ---- build L0 A-frags once: hi/lo f16 split of x, gathered per m-tile ----
    // d0=(xh0,xh1) d1=(xh2,xl0) d2=(xl1,xl2); frag = [d0,d1,d2,0] for ALL quads.
    f16x8 xfrag[4];
    {
        union { hfx2 h; int u; } q0_, q1_, q2_;
        q0_.h = __builtin_amdgcn_cvt_pkrtz(x0, x1);          // RTZ hi parts
        float r0 = x0 - (float)q0_.h[0];
        float r1 = x1 - (float)q0_.h[1];
        q1_.h = __builtin_amdgcn_cvt_pkrtz(x2, r0);
        float r2 = x2 - (float)q1_.h[0];
        q2_.h = __builtin_amdgcn_cvt_pkrtz(r1, r2);
        int d0 = q0_.u, d1 = q1_.u, d2 = q2_.u;
        #pragma unroll
        for (int mt = 0; mt < 4; ++mt) {
            int addr = 4 * (mt * 16 + col);                  // byte addr = lane*4
            union { int i[4]; f16x8 f; } u;
            u.i[0] = __builtin_amdgcn_ds_bpermute(addr, d0);
            u.i[1] = __builtin_amdgcn_ds_bpermute(addr, d1);
            u.i[2] = __builtin_amdgcn_ds_bpermute(addr, d2);
            u.i[3] = 0;
            xfrag[mt] = u.f;
        }
    }

    float res[4];
    const unsigned char* __restrict__ row = H + lane * HROW;

    #pragma unroll 1
    for (int b = 0; b < 4; ++b) {
        layer0_block(b, xfrag, W0f, B0p, H, col, quad);
        hidden_block(0, b, Wf, Bsc, H, col, quad);
        hidden_block(1, b, Wf, Bsc, H, col, quad);

        // ---------- layer 3: 32 -> 1 ----------
        uint4 u0 = *reinterpret_cast<const uint4*>(row);
        uint4 u1 = *reinterpret_cast<const uint4*>(row + 16);
        uint4 u2 = *reinterpret_cast<const uint4*>(row + 32);
        uint4 u3 = *reinterpret_cast<const uint4*>(row + 48);
        const uint4* wv4 = reinterpret_cast<const uint4*>(W3p + b * 16);
        uint4 w0 = wv4[0], w1 = wv4[1], w2 = wv4[2], w3v = wv4[3];
        float a0 = dot8(u0.x, u0.y, u0.z, u0.w, w0, b3[b]);
        float a1 = dot8(u1.x, u1.y, u1.z, u1.w, w1, 0.0f);
        float a2 = dot8(u2.x, u2.y, u2.z, u2.w, w2, 0.0f);
        float a3 = dot8(u3.x, u3.y, u3.z, u3.w, w3v, 0.0f);
        res[b] = (a0 + a1) + (a2 + a3);
    }

    float4 r4 = make_float4(res[0], res[1], res[2], res[3]);
    *reinterpret_cast<float4*>(out + 4 * n0) = r4;
}

extern "C" void kernel_launch(void* const* d_in, const int* in_sizes, int n_in,
                              void* d_out, int out_size, void* d_ws, size_t ws_size,
                              hipStream_t stream) {
    const float* x  = (const float*)d_in[0];
    const float* W0 = (const float*)d_in[1];
    const float* b0 = (const float*)d_in[2];
    const float* W1 = (const float*)d_in[3];
    const float* b1 = (const float*)d_in[4];
    const float* W2 = (const float*)d_in[5];
    const float* b2 = (const float*)d_in[6];
    const float* W3 = (const float*)d_in[7];
    const float* b3 = (const float*)d_in[8];
    float* out = (float*)d_out;
    unsigned char* ws = (unsigned char*)d_ws;

    prep_kernel<<<dim3(50), dim3(256), 0, stream>>>(W0, b0, W1, b1, W2, b2, W3, ws);
    pfnn_kernel<<<dim3(NPTS / BLOCK), dim3(BLOCK), 0, stream>>>(x, ws, b3, out);
}

// Round 9
// 159.170 us; speedup vs baseline: 1.2176x; 1.2176x over previous
//
#include <hip/hip_runtime.h>

// PFNN: 4 branches of 3->32->32->32->1 tanh MLP, N=1M points, fp32 in/out.
// Round 16: revert R15's CF-poly (scalarized f32x2 -> +60% VALU issue, 134us;
// lesson: packed-f32 pipelines lose when values are born scalar (exp2) and
// consumed scalar (cvt_pkrtz) - marshal movs eat the gain; 13-op scalar inv4c
// is the floor). Base = R14 (86.0us, proven). ONE change:
//   - mt-PAIRED layer blocks: issue 4 MFMAs (2 tiles), then both epilogues
//     adjacent -> scheduler sees 4 independent tanh4 chains (16 exp2 + 4 rcp
//     + ~52 VALU) to interleave; same-wave VALU fills trans-pipe latency.
//     +8 VGPR liveness only (scalars, no arrays, no loop-crossing = no R11/
//     R12 spill trigger). In-place H safe: stripe reads precede writes in
//     wave program order.
//   Discriminates: co-issue slack -> 79-84us; serialized issue -> neutral
//   (then R14 is ~97% issue-saturated: roofline).
//   - kept from R14: centered-inverse fold (-2*SCALE in W, h=-2*inv'),
//     13-op inv4c + batched rcp, tree dot8 + uint4 W3, float2 bias pairs,
//     MFMA L0 (hi/lo f16 split), HROW=80, launch_bounds(256,8).

#define NPTS 1048576
#define BLOCK 256
#define HROW 80          // bytes per h row in LDS (16B aligned)
#define SCALE 2.8853900817779268f   // 2*log2(e)

// ws layout (bytes):
// 0..16383   : WfH [2][4][2][16][32] f16 (hidden weights, -2*SCALE, permuted)
#define OFF_BSC  16384   // Bsc [2][4][16] float2 (hidden bias pairs, scaled)
#define OFF_W0F  17408   // W0f [4][2][16][32] f16 (L0 hi/lo packed, scaled)
#define OFF_B0P  25600   // B0p [4][16] float2 (L0 bias pairs, scaled)
#define OFF_W3P  26112   // W3p [4][16] u32 (f16 pairs of -2*w3)

using f16   = _Float16;
using f16x8 = __attribute__((ext_vector_type(8))) _Float16;  // MFMA A/B frag
using f32x4 = __attribute__((ext_vector_type(4))) float;     // MFMA C/D frag
using f32x2 = __attribute__((ext_vector_type(2))) float;     // f32 pair
using hfx2  = decltype(__builtin_amdgcn_cvt_pkrtz(0.0f, 0.0f)); // __fp16x2

// 4 centered inverses with ONE v_rcp: o_i = 1/(exp2(v_i)+1) - 0.5.
// (h = tanh = -2*o with pre-scaled v; the -2 is folded into next-layer W.)
// 13 VALU + 4 exp2 + 1 rcp - op-count floor for 4 divisions / 1 rcp.
__device__ __forceinline__ void inv4c(float v0, float v1, float v2, float v3,
                                      float& o0, float& o1, float& o2, float& o3)
{
    float a0 = __builtin_amdgcn_exp2f(v0) + 1.0f;
    float a1 = __builtin_amdgcn_exp2f(v1) + 1.0f;
    float a2 = __builtin_amdgcn_exp2f(v2) + 1.0f;
    float a3 = __builtin_amdgcn_exp2f(v3) + 1.0f;
    float p01 = a0 * a1;
    float p23 = a2 * a3;
    float p   = p01 * p23;
    float r   = __builtin_amdgcn_rcpf(p);
    float r01 = r * p23;            // 1/(a0*a1)
    float r23 = r * p01;            // 1/(a2*a3)
    o0 = __builtin_fmaf(r01, a1, -0.5f);   // 1/a0 - 0.5
    o1 = __builtin_fmaf(r01, a0, -0.5f);   // 1/a1 - 0.5
    o2 = __builtin_fmaf(r23, a3, -0.5f);   // 1/a2 - 0.5
    o3 = __builtin_fmaf(r23, a2, -0.5f);   // 1/a3 - 0.5
}

// per-mt epilogue: inv4c over (c0[r],c1[r],c0[r+1],c1[r+1]) -> 2 packed b32
__device__ __forceinline__ void epi_mt(const f32x4& c0, const f32x4& c1, int mt,
                                       unsigned char* __restrict__ H,
                                       int col, int quad)
{
    #pragma unroll
    for (int r = 0; r < 4; r += 2) {
        int p = mt * 16 + quad * 4 + r;
        float o0, o1, o2, o3;
        inv4c(c0[r], c1[r], c0[r + 1], c1[r + 1], o0, o1, o2, o3);
        union { hfx2 h; unsigned int u; } cv0, cv1;
        cv0.h = __builtin_amdgcn_cvt_pkrtz(o0, o1);
        cv1.h = __builtin_amdgcn_cvt_pkrtz(o2, o3);
        *reinterpret_cast<unsigned int*>(H + p * HROW + 4 * col)       = cv0.u;
        *reinterpret_cast<unsigned int*>(H + (p + 1) * HROW + 4 * col) = cv1.u;
    }
}

// layer 0 for branch b: 3 -> 32 via MFMA on xfrag, mt-PAIRED epilogues
__device__ __forceinline__ void layer0_block(int b, const f16x8 (&xfrag)[4],
                                             const f16* __restrict__ W0f,
                                             const float* __restrict__ B0p,
                                             unsigned char* __restrict__ H,
                                             int col, int quad)
{
    const f16* wb = W0f + (b * 2) * 512;
    f16x8 bf0 = *reinterpret_cast<const f16x8*>(wb + col * 32 + quad * 8);
    f16x8 bf1 = *reinterpret_cast<const f16x8*>(wb + 512 + col * 32 + quad * 8);
    const float2 bp = *reinterpret_cast<const float2*>(B0p + ((b * 16 + col) << 1));
    f32x4 ci0 = {bp.x, bp.x, bp.x, bp.x};   // shared C operand, all mt
    f32x4 ci1 = {bp.y, bp.y, bp.y, bp.y};

    #pragma unroll
    for (int mp = 0; mp < 2; ++mp) {
        const int mt0 = 2 * mp, mt1 = 2 * mp + 1;
        f32x4 c00 = __builtin_amdgcn_mfma_f32_16x16x32_f16(xfrag[mt0], bf0, ci0, 0, 0, 0);
        f32x4 c01 = __builtin_amdgcn_mfma_f32_16x16x32_f16(xfrag[mt0], bf1, ci1, 0, 0, 0);
        f32x4 c10 = __builtin_amdgcn_mfma_f32_16x16x32_f16(xfrag[mt1], bf0, ci0, 0, 0, 0);
        f32x4 c11 = __builtin_amdgcn_mfma_f32_16x16x32_f16(xfrag[mt1], bf1, ci1, 0, 0, 0);
        epi_mt(c00, c01, mt0, H, col, quad);
        epi_mt(c10, c11, mt1, H, col, quad);
    }
}

// hidden layer l (0->L1, 1->L2) for branch b: 32 -> 32, mt-PAIRED.
// In-place H: both stripes' ds_reads issue BEFORE either stripe's epi writes
// (wave program order) -> safe; each stripe overwrites only rows it read.
__device__ __forceinline__ void hidden_block(int l, int b,
                                             const f16* __restrict__ Wf,
                                             const float* __restrict__ Bsc,
                                             unsigned char* __restrict__ H,
                                             int col, int quad)
{
    const f16* wb = Wf + ((l * 4 + b) * 2) * 512;
    f16x8 bf0 = *reinterpret_cast<const f16x8*>(wb + col * 32 + quad * 8);
    f16x8 bf1 = *reinterpret_cast<const f16x8*>(wb + 512 + col * 32 + quad * 8);
    const float2 bp = *reinterpret_cast<const float2*>(
        Bsc + (((l * 4 + b) * 16 + col) << 1));
    f32x4 ci0 = {bp.x, bp.x, bp.x, bp.x};   // shared C operand, all mt
    f32x4 ci1 = {bp.y, bp.y, bp.y, bp.y};

    #pragma unroll
    for (int mp = 0; mp < 2; ++mp) {
        const int mt0 = 2 * mp, mt1 = 2 * mp + 1;
        const f16x8 av0 = *reinterpret_cast<const f16x8*>(
            H + (mt0 * 16 + col) * HROW + quad * 16);   // 16B aligned
        const f16x8 av1 = *reinterpret_cast<const f16x8*>(
            H + (mt1 * 16 + col) * HROW + quad * 16);
        f32x4 c00 = __builtin_amdgcn_mfma_f32_16x16x32_f16(av0, bf0, ci0, 0, 0, 0);
        f32x4 c01 = __builtin_amdgcn_mfma_f32_16x16x32_f16(av0, bf1, ci1, 0, 0, 0);
        f32x4 c10 = __builtin_amdgcn_mfma_f32_16x16x32_f16(av1, bf0, ci0, 0, 0, 0);
        f32x4 c11 = __builtin_amdgcn_mfma_f32_16x16x32_f16(av1, bf1, ci1, 0, 0, 0);
        epi_mt(c00, c01, mt0, H, col, quad);
        epi_mt(c10, c11, mt1, H, col, quad);
    }
}

// 8-element f16 dot: acc += sum(u[i]*w[i]) via fdot2/fma
__device__ __forceinline__ float dot8(unsigned int ux, unsigned int uy,
                                      unsigned int uz, unsigned int uw,
                                      uint4 w, float acc)
{
#if __has_builtin(__builtin_amdgcn_fdot2)
    union { unsigned int uu; hfx2 hh; } a0, a1, a2, a3, b0, b1, b2, b3;
    a0.uu = ux; a1.uu = uy; a2.uu = uz; a3.uu = uw;
    b0.uu = w.x; b1.uu = w.y; b2.uu = w.z; b3.uu = w.w;
    acc = __builtin_amdgcn_fdot2(a0.hh, b0.hh, acc, false);
    acc = __builtin_amdgcn_fdot2(a1.hh, b1.hh, acc, false);
    acc = __builtin_amdgcn_fdot2(a2.hh, b2.hh, acc, false);
    acc = __builtin_amdgcn_fdot2(a3.hh, b3.hh, acc, false);
#else
    union { unsigned int uu; f16 h[2]; } a[4], bw[4];
    a[0].uu = ux; a[1].uu = uy; a[2].uu = uz; a[3].uu = uw;
    bw[0].uu = w.x; bw[1].uu = w.y; bw[2].uu = w.z; bw[3].uu = w.w;
    #pragma unroll
    for (int q = 0; q < 4; ++q) {
        acc = __builtin_fmaf((float)a[q].h[0], (float)bw[q].h[0], acc);
        acc = __builtin_fmaf((float)a[q].h[1], (float)bw[q].h[1], acc);
    }
#endif
    return acc;
}

__global__ void prep_kernel(const float* __restrict__ W0, const float* __restrict__ b0,
                            const float* __restrict__ W1, const float* __restrict__ b1,
                            const float* __restrict__ W2, const float* __restrict__ b2,
                            const float* __restrict__ W3,
                            unsigned char* __restrict__ ws)
{
    int i = blockIdx.x * 256 + threadIdx.x;
    if (i < 8192) {
        // WfH[l][b][t][n][k] = -2 * SCALE * W_l[b][k][2n+t]  (f16)
        int k = i & 31, n = (i >> 5) & 15, t = (i >> 9) & 1, b = (i >> 10) & 3, l = i >> 12;
        int f = 2 * n + t;
        const float* W = l ? W2 : W1;
        reinterpret_cast<f16*>(ws)[i] = (f16)(-2.0f * SCALE * W[(b * 32 + k) * 32 + f]);
    } else if (i < 8448) {
        // Bsc pairs: [(l*4+b)*16+n] -> (bias_even, bias_odd)
        int j = i - 8192;
        int n = j & 15, t = (j >> 4) & 1, b = (j >> 5) & 3, l = j >> 7;
        const float* bb = l ? b2 : b1;
        reinterpret_cast<float*>(ws + OFF_BSC)[(((l * 4 + b) * 16 + n) << 1) | t]
            = SCALE * bb[b * 32 + 2 * n + t];
    } else if (i < 12544) {
        // W0f[b][t][n][k]: quad q = k>>3, jj = k&7.
        //   q==0, jj<3 : Wh row jj      (pairs with xh -> xh*Wh)
        //   q==0, 3<=jj<6 : Wh row jj-3 (pairs with xl -> xl*Wh)
        //   q==1, jj<3 : Wl row jj      (pairs with xh -> xh*Wl)
        //   else 0
        int j = i - 8448;
        int k = j & 31, n = (j >> 5) & 15, t = (j >> 9) & 1, b = (j >> 10) & 3;
        int f = 2 * n + t;
        int q = k >> 3, jj = k & 7;
        int row = -1; bool lo = false;
        if (q == 0 && jj < 6)      row = (jj < 3) ? jj : jj - 3;
        else if (q == 1 && jj < 3) { row = jj; lo = true; }
        f16 outv = (f16)0.0f;
        if (row >= 0) {
            float w  = SCALE * W0[(b * 3 + row) * 32 + f];
            f16   wh = (f16)w;
            outv = lo ? (f16)(w - (float)wh) : wh;
        }
        reinterpret_cast<f16*>(ws + OFF_W0F)[((b * 2 + t) * 16 + n) * 32 + k] = outv;
    } else if (i < 12672) {
        // B0p pairs: [b*16+n] -> (bias_even, bias_odd)
        int j = i - 12544;
        int n = j & 15, t = (j >> 4) & 1, b = j >> 5;
        reinterpret_cast<float*>(ws + OFF_B0P)[(((b) * 16 + n) << 1) | t]
            = SCALE * b0[b * 32 + 2 * n + t];
    } else if (i < 12736) {
        int j = i - 12672;              // j = b*16 + pair
        union { hfx2 h; unsigned int u; } cv;
        cv.h = __builtin_amdgcn_cvt_pkrtz(-2.0f * W3[2 * j], -2.0f * W3[2 * j + 1]);
        reinterpret_cast<unsigned int*>(ws + OFF_W3P)[j] = cv.u;
    }
}

__global__ __launch_bounds__(BLOCK, 8) void pfnn_kernel(
    const float* __restrict__ x, const unsigned char* __restrict__ ws,
    const float* __restrict__ b3,
    float* __restrict__ out)
{
    __shared__ __align__(16) unsigned char Hl[4][64 * HROW]; // per-wave h tile

    const f16*   Wf  = reinterpret_cast<const f16*>(ws);
    const float* Bsc = reinterpret_cast<const float*>(ws + OFF_BSC);
    const f16*   W0f = reinterpret_cast<const f16*>(ws + OFF_W0F);
    const float* B0p = reinterpret_cast<const float*>(ws + OFF_B0P);
    const unsigned int* W3p = reinterpret_cast<const unsigned int*>(ws + OFF_W3P);

    const int t    = threadIdx.x;
    const int lane = t & 63;
    const int wv   = t >> 6;
    const int col  = lane & 15;
    const int quad = lane >> 4;
    unsigned char* __restrict__ H = &Hl[wv][0];

    const int n0 = blockIdx.x * BLOCK + t;
    const float x0 = x[3 * n0 + 0];
    const float x1 = x[3 * n0 + 1];
    const float x2 = x[3 * n0 + 2];

    // ---- build L0 A-frags once: hi/lo f16 split of x, gathered per m-tile ----
    // d0=(xh0,xh1) d1=(xh2,xl0) d2=(xl1,xl2); frag = [d0,d1,d2,0] for ALL quads.
    f16x8 xfrag[4];
    {
        union { hfx2 h; int u; } q0_, q1_, q2_;
        q0_.h = __builtin_amdgcn_cvt_pkrtz(x0, x1);          // RTZ hi parts
        float r0 = x0 - (float)q0_.h[0];
        float r1 = x1 - (float)q0_.h[1];
        q1_.h = __builtin_amdgcn_cvt_pkrtz(x2, r0);
        float r2 = x2 - (float)q1_.h[0];
        q2_.h = __builtin_amdgcn_cvt_pkrtz(r1, r2);
        int d0 = q0_.u, d1 = q1_.u, d2 = q2_.u;
        #pragma unroll
        for (int mt = 0; mt < 4; ++mt) {
            int addr = 4 * (mt * 16 + col);                  // byte addr = lane*4
            union { int i[4]; f16x8 f; } u;
            u.i[0] = __builtin_amdgcn_ds_bpermute(addr, d0);
            u.i[1] = __builtin_amdgcn_ds_bpermute(addr, d1);
            u.i[2] = __builtin_amdgcn_ds_bpermute(addr, d2);
            u.i[3] = 0;
            xfrag[mt] = u.f;
        }
    }

    float res[4];
    const unsigned char* __restrict__ row = H + lane * HROW;

    #pragma unroll 1
    for (int b = 0; b < 4; ++b) {
        layer0_block(b, xfrag, W0f, B0p, H, col, quad);
        hidden_block(0, b, Wf, Bsc, H, col, quad);
        hidden_block(1, b, Wf, Bsc, H, col, quad);

        // ---------- layer 3: 32 -> 1 (weights pre-multiplied by -2) ----------
        uint4 u0 = *reinterpret_cast<const uint4*>(row);
        uint4 u1 = *reinterpret_cast<const uint4*>(row + 16);
        uint4 u2 = *reinterpret_cast<const uint4*>(row + 32);
        uint4 u3 = *reinterpret_cast<const uint4*>(row + 48);
        const uint4* wv4 = reinterpret_cast<const uint4*>(W3p + b * 16);
        uint4 w0 = wv4[0], w1 = wv4[1], w2 = wv4[2], w3v = wv4[3];
        float a0 = dot8(u0.x, u0.y, u0.z, u0.w, w0, b3[b]);
        float a1 = dot8(u1.x, u1.y, u1.z, u1.w, w1, 0.0f);
        float a2 = dot8(u2.x, u2.y, u2.z, u2.w, w2, 0.0f);
        float a3 = dot8(u3.x, u3.y, u3.z, u3.w, w3v, 0.0f);
        res[b] = (a0 + a1) + (a2 + a3);
    }

    float4 r4 = make_float4(res[0], res[1], res[2], res[3]);
    *reinterpret_cast<float4*>(out + 4 * n0) = r4;
}

extern "C" void kernel_launch(void* const* d_in, const int* in_sizes, int n_in,
                              void* d_out, int out_size, void* d_ws, size_t ws_size,
                              hipStream_t stream) {
    const float* x  = (const float*)d_in[0];
    const float* W0 = (const float*)d_in[1];
    const float* b0 = (const float*)d_in[2];
    const float* W1 = (const float*)d_in[3];
    const float* b1 = (const float*)d_in[4];
    const float* W2 = (const float*)d_in[5];
    const float* b2 = (const float*)d_in[6];
    const float* W3 = (const float*)d_in[7];
    const float* b3 = (const float*)d_in[8];
    float* out = (float*)d_out;
    unsigned char* ws = (unsigned char*)d_ws;

    prep_kernel<<<dim3(50), dim3(256), 0, stream>>>(W0, b0, W1, b1, W2, b2, W3, ws);
    pfnn_kernel<<<dim3(NPTS / BLOCK), dim3(BLOCK), 0, stream>>>(x, ws, b3, out);
}

// Round 10
// 158.100 us; speedup vs baseline: 1.2258x; 1.0068x over previous
//
#include <hip/hip_runtime.h>

// PFNN: 4 branches of 3->32->32->32->1 tanh MLP, N=1M points, fp32 in/out.
// Round 17: revert R16 mt-pairing (3rd spill-pathology regression: AGPR
// copy shuttling, WRITE 16->25MB, +13% VALU issue). Lesson locked in: this
// allocator pins ~32 arch VGPRs; ANY extended accumulator liveness becomes
// AGPR-copies/scratch, so ILP-widening at HIP source is closed.
// Base = R14 (86.0us, proven). ONE change - block granularity:
//   - BLOCK 256 -> 128 (2 waves, 10KiB LDS): 16 blocks/CU instead of 8 at
//     the same 32-wave/CU ceiling. Achieved occupancy has been pinned at
//     ~66% in every clean run; 4-wave/20KiB blocks leave 4-wave holes on
//     drain. 2-wave quanta pack finer -> more resident waves -> stall
//     cycles (the ~30% idle) get filled. Per-thread code byte-identical.
//   Discriminator: OccupancyPercent 66 -> 73-80 => dur 80-84us; flat 66 =>
//   neutral, R14 structure is the practical ceiling.
//   - kept from R14: centered-inverse fold (-2*SCALE in W, h=-2*inv'),
//     13-op scalar inv4c + batched rcp (op-count floor), tree dot8 + uint4
//     W3 loads, float2 bias pairs, MFMA L0 (hi/lo f16 split of x),
//     HROW=80 b128 A-reads, per-wave LDS h tile.

#define NPTS 1048576
#define BLOCK 128
#define NWAVE (BLOCK / 64)
#define HROW 80          // bytes per h row in LDS (16B aligned)
#define SCALE 2.8853900817779268f   // 2*log2(e)

// ws layout (bytes):
// 0..16383   : WfH [2][4][2][16][32] f16 (hidden weights, -2*SCALE, permuted)
#define OFF_BSC  16384   // Bsc [2][4][16] float2 (hidden bias pairs, scaled)
#define OFF_W0F  17408   // W0f [4][2][16][32] f16 (L0 hi/lo packed, scaled)
#define OFF_B0P  25600   // B0p [4][16] float2 (L0 bias pairs, scaled)
#define OFF_W3P  26112   // W3p [4][16] u32 (f16 pairs of -2*w3)

using f16   = _Float16;
using f16x8 = __attribute__((ext_vector_type(8))) _Float16;  // MFMA A/B frag
using f32x4 = __attribute__((ext_vector_type(4))) float;     // MFMA C/D frag
using hfx2  = decltype(__builtin_amdgcn_cvt_pkrtz(0.0f, 0.0f)); // __fp16x2

// 4 centered inverses with ONE v_rcp: o_i = 1/(exp2(v_i)+1) - 0.5.
// (h = tanh = -2*o with pre-scaled v; the -2 is folded into next-layer W.)
// 13 VALU + 4 exp2 + 1 rcp - op-count floor for 4 divisions / 1 rcp.
__device__ __forceinline__ void inv4c(float v0, float v1, float v2, float v3,
                                      float& o0, float& o1, float& o2, float& o3)
{
    float a0 = __builtin_amdgcn_exp2f(v0) + 1.0f;
    float a1 = __builtin_amdgcn_exp2f(v1) + 1.0f;
    float a2 = __builtin_amdgcn_exp2f(v2) + 1.0f;
    float a3 = __builtin_amdgcn_exp2f(v3) + 1.0f;
    float p01 = a0 * a1;
    float p23 = a2 * a3;
    float p   = p01 * p23;
    float r   = __builtin_amdgcn_rcpf(p);
    float r01 = r * p23;            // 1/(a0*a1)
    float r23 = r * p01;            // 1/(a2*a3)
    o0 = __builtin_fmaf(r01, a1, -0.5f);   // 1/a0 - 0.5
    o1 = __builtin_fmaf(r01, a0, -0.5f);   // 1/a1 - 0.5
    o2 = __builtin_fmaf(r23, a3, -0.5f);   // 1/a2 - 0.5
    o3 = __builtin_fmaf(r23, a2, -0.5f);   // 1/a3 - 0.5
}

// per-mt epilogue: inv4c over (c0[r],c1[r],c0[r+1],c1[r+1]) -> 2 packed b32
__device__ __forceinline__ void epi_mt(const f32x4& c0, const f32x4& c1, int mt,
                                       unsigned char* __restrict__ H,
                                       int col, int quad)
{
    #pragma unroll
    for (int r = 0; r < 4; r += 2) {
        int p = mt * 16 + quad * 4 + r;
        float o0, o1, o2, o3;
        inv4c(c0[r], c1[r], c0[r + 1], c1[r + 1], o0, o1, o2, o3);
        union { hfx2 h; unsigned int u; } cv0, cv1;
        cv0.h = __builtin_amdgcn_cvt_pkrtz(o0, o1);
        cv1.h = __builtin_amdgcn_cvt_pkrtz(o2, o3);
        *reinterpret_cast<unsigned int*>(H + p * HROW + 4 * col)       = cv0.u;
        *reinterpret_cast<unsigned int*>(H + (p + 1) * HROW + 4 * col) = cv1.u;
    }
}

// layer 0 for branch b: 3 -> 32 via MFMA on xfrag (fp32-equivalent)
__device__ __forceinline__ void layer0_block(int b, const f16x8 (&xfrag)[4],
                                             const f16* __restrict__ W0f,
                                             const float* __restrict__ B0p,
                                             unsigned char* __restrict__ H,
                                             int col, int quad)
{
    const f16* wb = W0f + (b * 2) * 512;
    f16x8 bf0 = *reinterpret_cast<const f16x8*>(wb + col * 32 + quad * 8);
    f16x8 bf1 = *reinterpret_cast<const f16x8*>(wb + 512 + col * 32 + quad * 8);
    const float2 bp = *reinterpret_cast<const float2*>(B0p + ((b * 16 + col) << 1));
    f32x4 ci0 = {bp.x, bp.x, bp.x, bp.x};   // shared C operand, all mt
    f32x4 ci1 = {bp.y, bp.y, bp.y, bp.y};

    #pragma unroll
    for (int mt = 0; mt < 4; ++mt) {
        f32x4 c0 = __builtin_amdgcn_mfma_f32_16x16x32_f16(xfrag[mt], bf0, ci0, 0, 0, 0);
        f32x4 c1 = __builtin_amdgcn_mfma_f32_16x16x32_f16(xfrag[mt], bf1, ci1, 0, 0, 0);
        epi_mt(c0, c1, mt, H, col, quad);
    }
}

// hidden layer l (0->L1, 1->L2) for branch b: 32 -> 32 via MFMA from H
__device__ __forceinline__ void hidden_block(int l, int b,
                                             const f16* __restrict__ Wf,
                                             const float* __restrict__ Bsc,
                                             unsigned char* __restrict__ H,
                                             int col, int quad)
{
    const f16* wb = Wf + ((l * 4 + b) * 2) * 512;
    f16x8 bf0 = *reinterpret_cast<const f16x8*>(wb + col * 32 + quad * 8);
    f16x8 bf1 = *reinterpret_cast<const f16x8*>(wb + 512 + col * 32 + quad * 8);
    const float2 bp = *reinterpret_cast<const float2*>(
        Bsc + (((l * 4 + b) * 16 + col) << 1));
    f32x4 ci0 = {bp.x, bp.x, bp.x, bp.x};   // shared C operand, all mt
    f32x4 ci1 = {bp.y, bp.y, bp.y, bp.y};

    #pragma unroll
    for (int mt = 0; mt < 4; ++mt) {
        const f16x8 av = *reinterpret_cast<const f16x8*>(
            H + (mt * 16 + col) * HROW + quad * 16);   // 16B aligned
        f32x4 c0 = __builtin_amdgcn_mfma_f32_16x16x32_f16(av, bf0, ci0, 0, 0, 0);
        f32x4 c1 = __builtin_amdgcn_mfma_f32_16x16x32_f16(av, bf1, ci1, 0, 0, 0);
        epi_mt(c0, c1, mt, H, col, quad);
    }
}

// 8-element f16 dot: acc += sum(u[i]*w[i]) via fdot2/fma
__device__ __forceinline__ float dot8(unsigned int ux, unsigned int uy,
                                      unsigned int uz, unsigned int uw,
                                      uint4 w, float acc)
{
#if __has_builtin(__builtin_amdgcn_fdot2)
    union { unsigned int uu; hfx2 hh; } a0, a1, a2, a3, b0, b1, b2, b3;
    a0.uu = ux; a1.uu = uy; a2.uu = uz; a3.uu = uw;
    b0.uu = w.x; b1.uu = w.y; b2.uu = w.z; b3.uu = w.w;
    acc = __builtin_amdgcn_fdot2(a0.hh, b0.hh, acc, false);
    acc = __builtin_amdgcn_fdot2(a1.hh, b1.hh, acc, false);
    acc = __builtin_amdgcn_fdot2(a2.hh, b2.hh, acc, false);
    acc = __builtin_amdgcn_fdot2(a3.hh, b3.hh, acc, false);
#else
    union { unsigned int uu; f16 h[2]; } a[4], bw[4];
    a[0].uu = ux; a[1].uu = uy; a[2].uu = uz; a[3].uu = uw;
    bw[0].uu = w.x; bw[1].uu = w.y; bw[2].uu = w.z; bw[3].uu = w.w;
    #pragma unroll
    for (int q = 0; q < 4; ++q) {
        acc = __builtin_fmaf((float)a[q].h[0], (float)bw[q].h[0], acc);
        acc = __builtin_fmaf((float)a[q].h[1], (float)bw[q].h[1], acc);
    }
#endif
    return acc;
}

__global__ void prep_kernel(const float* __restrict__ W0, const float* __restrict__ b0,
                            const float* __restrict__ W1, const float* __restrict__ b1,
                            const float* __restrict__ W2, const float* __restrict__ b2,
                            const float* __restrict__ W3,
                            unsigned char* __restrict__ ws)
{
    int i = blockIdx.x * 256 + threadIdx.x;
    if (i < 8192) {
        // WfH[l][b][t][n][k] = -2 * SCALE * W_l[b][k][2n+t]  (f16)
        int k = i & 31, n = (i >> 5) & 15, t = (i >> 9) & 1, b = (i >> 10) & 3, l = i >> 12;
        int f = 2 * n + t;
        const float* W = l ? W2 : W1;
        reinterpret_cast<f16*>(ws)[i] = (f16)(-2.0f * SCALE * W[(b * 32 + k) * 32 + f]);
    } else if (i < 8448) {
        // Bsc pairs: [(l*4+b)*16+n] -> (bias_even, bias_odd)
        int j = i - 8192;
        int n = j & 15, t = (j >> 4) & 1, b = (j >> 5) & 3, l = j >> 7;
        const float* bb = l ? b2 : b1;
        reinterpret_cast<float*>(ws + OFF_BSC)[(((l * 4 + b) * 16 + n) << 1) | t]
            = SCALE * bb[b * 32 + 2 * n + t];
    } else if (i < 12544) {
        // W0f[b][t][n][k]: quad q = k>>3, jj = k&7.
        //   q==0, jj<3 : Wh row jj      (pairs with xh -> xh*Wh)
        //   q==0, 3<=jj<6 : Wh row jj-3 (pairs with xl -> xl*Wh)
        //   q==1, jj<3 : Wl row jj      (pairs with xh -> xh*Wl)
        //   else 0
        int j = i - 8448;
        int k = j & 31, n = (j >> 5) & 15, t = (j >> 9) & 1, b = (j >> 10) & 3;
        int f = 2 * n + t;
        int q = k >> 3, jj = k & 7;
        int row = -1; bool lo = false;
        if (q == 0 && jj < 6)      row = (jj < 3) ? jj : jj - 3;
        else if (q == 1 && jj < 3) { row = jj; lo = true; }
        f16 outv = (f16)0.0f;
        if (row >= 0) {
            float w  = SCALE * W0[(b * 3 + row) * 32 + f];
            f16   wh = (f16)w;
            outv = lo ? (f16)(w - (float)wh) : wh;
        }
        reinterpret_cast<f16*>(ws + OFF_W0F)[((b * 2 + t) * 16 + n) * 32 + k] = outv;
    } else if (i < 12672) {
        // B0p pairs: [b*16+n] -> (bias_even, bias_odd)
        int j = i - 12544;
        int n = j & 15, t = (j >> 4) & 1, b = j >> 5;
        reinterpret_cast<float*>(ws + OFF_B0P)[(((b) * 16 + n) << 1) | t]
            = SCALE * b0[b * 32 + 2 * n + t];
    } else if (i < 12736) {
        int j = i - 12672;              // j = b*16 + pair
        union { hfx2 h; unsigned int u; } cv;
        cv.h = __builtin_amdgcn_cvt_pkrtz(-2.0f * W3[2 * j], -2.0f * W3[2 * j + 1]);
        reinterpret_cast<unsigned int*>(ws + OFF_W3P)[j] = cv.u;
    }
}

__global__ __launch_bounds__(BLOCK, 8) void pfnn_kernel(
    const float* __restrict__ x, const unsigned char* __restrict__ ws,
    const float* __restrict__ b3,
    float* __restrict__ out)
{
    __shared__ __align__(16) unsigned char Hl[NWAVE][64 * HROW]; // per-wave h tile

    const f16*   Wf  = reinterpret_cast<const f16*>(ws);
    const float* Bsc = reinterpret_cast<const float*>(ws + OFF_BSC);
    const f16*   W0f = reinterpret_cast<const f16*>(ws + OFF_W0F);
    const float* B0p = reinterpret_cast<const float*>(ws + OFF_B0P);
    const unsigned int* W3p = reinterpret_cast<const unsigned int*>(ws + OFF_W3P);

    const int t    = threadIdx.x;
    const int lane = t & 63;
    const int wv   = t >> 6;
    const int col  = lane & 15;
    const int quad = lane >> 4;
    unsigned char* __restrict__ H = &Hl[wv][0];

    const int n0 = blockIdx.x * BLOCK + t;
    const float x0 = x[3 * n0 + 0];
    const float x1 = x[3 * n0 + 1];
    const float x2 = x[3 * n0 + 2];

    // ---- build L0 A-frags once: hi/lo f16 split of x, gathered per m-tile ----
    // d0=(xh0,xh1) d1=(xh2,xl0) d2=(xl1,xl2); frag = [d0,d1,d2,0] for ALL quads.
    f16x8 xfrag[4];
    {
        union { hfx2 h; int u; } q0_, q1_, q2_;
        q0_.h = __builtin_amdgcn_cvt_pkrtz(x0, x1);          // RTZ hi parts
        float r0 = x0 - (float)q0_.h[0];
        float r1 = x1 - (float)q0_.h[1];
        q1_.h = __builtin_amdgcn_cvt_pkrtz(x2, r0);
        float r2 = x2 - (float)q1_.h[0];
        q2_.h = __builtin_amdgcn_cvt_pkrtz(r1, r2);
        int d0 = q0_.u, d1 = q1_.u, d2 = q2_.u;
        #pragma unroll
        for (int mt = 0; mt < 4; ++mt) {
            int addr = 4 * (mt * 16 + col);                  // byte addr = lane*4
            union { int i[4]; f16x8 f; } u;
            u.i[0] = __builtin_amdgcn_ds_bpermute(addr, d0);
            u.i[1] = __builtin_amdgcn_ds_bpermute(addr, d1);
            u.i[2] = __builtin_amdgcn_ds_bpermute(addr, d2);
            u.i[3] = 0;
            xfrag[mt] = u.f;
        }
    }

    float res[4];
    const unsigned char* __restrict__ row = H + lane * HROW;

    #pragma unroll 1
    for (int b = 0; b < 4; ++b) {
        layer0_block(b, xfrag, W0f, B0p, H, col, quad);
        hidden_block(0, b, Wf, Bsc, H, col, quad);
        hidden_block(1, b, Wf, Bsc, H, col, quad);

        // ---------- layer 3: 32 -> 1 (weights pre-multiplied by -2) ----------
        uint4 u0 = *reinterpret_cast<const uint4*>(row);
        uint4 u1 = *reinterpret_cast<const uint4*>(row + 16);
        uint4 u2 = *reinterpret_cast<const uint4*>(row + 32);
        uint4 u3 = *reinterpret_cast<const uint4*>(row + 48);
        const uint4* wv4 = reinterpret_cast<const uint4*>(W3p + b * 16);
        uint4 w0 = wv4[0], w1 = wv4[1], w2 = wv4[2], w3v = wv4[3];
        float a0 = dot8(u0.x, u0.y, u0.z, u0.w, w0, b3[b]);
        float a1 = dot8(u1.x, u1.y, u1.z, u1.w, w1, 0.0f);
        float a2 = dot8(u2.x, u2.y, u2.z, u2.w, w2, 0.0f);
        float a3 = dot8(u3.x, u3.y, u3.z, u3.w, w3v, 0.0f);
        res[b] = (a0 + a1) + (a2 + a3);
    }

    float4 r4 = make_float4(res[0], res[1], res[2], res[3]);
    *reinterpret_cast<float4*>(out + 4 * n0) = r4;
}

extern "C" void kernel_launch(void* const* d_in, const int* in_sizes, int n_in,
                              void* d_out, int out_size, void* d_ws, size_t ws_size,
                              hipStream_t stream) {
    const float* x  = (const float*)d_in[0];
    const float* W0 = (const float*)d_in[1];
    const float* b0 = (const float*)d_in[2];
    const float* W1 = (const float*)d_in[3];
    const float* b1 = (const float*)d_in[4];
    const float* W2 = (const float*)d_in[5];
    const float* b2 = (const float*)d_in[6];
    const float* W3 = (const float*)d_in[7];
    const float* b3 = (const float*)d_in[8];
    float* out = (float*)d_out;
    unsigned char* ws = (unsigned char*)d_ws;

    prep_kernel<<<dim3(50), dim3(256), 0, stream>>>(W0, b0, W1, b1, W2, b2, W3, ws);
    pfnn_kernel<<<dim3(NPTS / BLOCK), dim3(BLOCK), 0, stream>>>(x, ws, b3, out);
}